// Round 1
// baseline (1141.894 us; speedup 1.0000x reference)
//
#include <hip/hip_runtime.h>

#define NN 100000
#define NE 1000000
#define DIM 64

// Transform kernel: for each node n,
//   h[n][0][:] = act(x[n]) @ W0
//   h[n][1][:] = act(x[n]) @ W1
//   out[n][:]  = act(x[n]) @ Ws + b      (init value for edge aggregation)
// act = relu if relu_in else identity (relu applied on READ of previous layer's
// pre-activation output; final layer output correctly stays pre-activation).
// One wave per node; lane j owns output dim j; __shfl broadcasts x[d].
// NOTE: x and out may alias (in-place layer): row n is read fully before the
// single write to row n within the same wave, and each row is owned by exactly
// one wave -> safe. Do NOT mark x/out __restrict__.
__global__ __launch_bounds__(256) void rgcn_transform(
    const float* x, const float* __restrict__ W,
    const float* __restrict__ Ws, const float* __restrict__ b,
    float* __restrict__ h, float* out, int relu_in)
{
    __shared__ float sW0[DIM * DIM];
    __shared__ float sW1[DIM * DIM];
    __shared__ float sWs[DIM * DIM];
    __shared__ float sb[DIM];

    int t = threadIdx.x;
    for (int i = t; i < DIM * DIM; i += 256) {
        sW0[i] = W[i];
        sW1[i] = W[DIM * DIM + i];
        sWs[i] = Ws[i];
    }
    if (t < DIM) sb[t] = b[t];
    __syncthreads();

    int lane = t & 63;
    int wid  = t >> 6;
    int gw     = blockIdx.x * 4 + wid;
    int stride = gridDim.x * 4;

    for (int n = gw; n < NN; n += stride) {
        float xv = x[n * DIM + lane];
        if (relu_in) xv = fmaxf(xv, 0.0f);
        float a0 = 0.0f, a1 = 0.0f, as = sb[lane];
#pragma unroll
        for (int d = 0; d < DIM; ++d) {
            float xd = __shfl(xv, d, 64);
            a0 = fmaf(xd, sW0[d * DIM + lane], a0);
            a1 = fmaf(xd, sW1[d * DIM + lane], a1);
            as = fmaf(xd, sWs[d * DIM + lane], as);
        }
        h[(size_t)n * (2 * DIM) + lane]       = a0;
        h[(size_t)n * (2 * DIM) + DIM + lane] = a1;
        out[(size_t)n * DIM + lane] = as;
    }
}

// Edge scatter: one wave per edge. Coalesced 256B gather of h[src][etype],
// 64 contiguous fp32 atomicAdds into out[dst].
__global__ __launch_bounds__(256) void rgcn_scatter(
    const float* __restrict__ h, const int* __restrict__ src,
    const int* __restrict__ dst, const int* __restrict__ et,
    float* __restrict__ out)
{
    int idx  = blockIdx.x * 256 + threadIdx.x;
    int e    = idx >> 6;
    int lane = idx & 63;
    if (e >= NE) return;
    int s = src[e];
    int d = dst[e];
    int r = et[e];
    float v = h[(size_t)s * (2 * DIM) + r * DIM + lane];
    atomicAdd(&out[(size_t)d * DIM + lane], v);
}

extern "C" void kernel_launch(void* const* d_in, const int* in_sizes, int n_in,
                              void* d_out, int out_size, void* d_ws, size_t ws_size,
                              hipStream_t stream)
{
    const float* feat = (const float*)d_in[0];
    const int*   src  = (const int*)d_in[1];
    const int*   dst  = (const int*)d_in[2];
    const int*   et   = (const int*)d_in[3];
    const float* W[3]  = { (const float*)d_in[4], (const float*)d_in[7], (const float*)d_in[10] };
    const float* Ws[3] = { (const float*)d_in[5], (const float*)d_in[8], (const float*)d_in[11] };
    const float* b[3]  = { (const float*)d_in[6], (const float*)d_in[9], (const float*)d_in[12] };

    // Workspace layout: h [NN][2][DIM] fp32, then bufA [NN][DIM] fp32.
    // Total = NN*192*4 = 76.8 MB.
    float* h    = (float*)d_ws;
    float* bufA = h + (size_t)NN * 2 * DIM;
    float* outF = (float*)d_out;

    const dim3 tb(256);
    const int tgrid = 1024;                  // grid-stride over nodes
    const int sgrid = (NE * 64) / 256;       // 250000 blocks, 4 edges each

    // Layer 0: input = features (no relu on read)
    rgcn_transform<<<tgrid, tb, 0, stream>>>(feat, W[0], Ws[0], b[0], h, bufA, 0);
    rgcn_scatter<<<sgrid, tb, 0, stream>>>(h, src, dst, et, bufA);

    // Layer 1: in-place on bufA (relu on read)
    rgcn_transform<<<tgrid, tb, 0, stream>>>(bufA, W[1], Ws[1], b[1], h, bufA, 1);
    rgcn_scatter<<<sgrid, tb, 0, stream>>>(h, src, dst, et, bufA);

    // Layer 2: output to d_out (relu on read, no final activation)
    rgcn_transform<<<tgrid, tb, 0, stream>>>(bufA, W[2], Ws[2], b[2], h, outF, 1);
    rgcn_scatter<<<sgrid, tb, 0, stream>>>(h, src, dst, et, outF);
}

// Round 2
// 833.158 us; speedup vs baseline: 1.3706x; 1.3706x over previous
//
#include <hip/hip_runtime.h>

#define NN 100000
#define NE 1000000
#define DIM 64
#define TNODES 32   // nodes per transform block tile

// ---------------- CSR build (once per call, reused by all 3 layers) ----------
__global__ __launch_bounds__(256) void zero_counts(int* cnt) {
    int i = blockIdx.x * 256 + threadIdx.x;
    if (i < NN) cnt[i] = 0;
}

__global__ __launch_bounds__(256) void count_dst(const int* __restrict__ dst,
                                                 int* __restrict__ cnt) {
    int e = blockIdx.x * 256 + threadIdx.x;
    if (e < NE) atomicAdd(&cnt[dst[e]], 1);
}

// Single-block exclusive scan over NN counts -> row_ptr; cursor = copy for fill.
__global__ __launch_bounds__(1024) void scan_counts(const int* __restrict__ cnt,
                                                    int* __restrict__ row_ptr,
                                                    int* __restrict__ cursor) {
    __shared__ int part[1024];
    int t = threadIdx.x;
    const int C = (NN + 1023) / 1024;  // 98 elems per thread
    int lo = t * C, hi = lo + C; if (hi > NN) hi = NN;
    int s = 0;
    for (int i = lo; i < hi; ++i) s += cnt[i];
    part[t] = s;
    __syncthreads();
    for (int off = 1; off < 1024; off <<= 1) {
        int v = (t >= off) ? part[t - off] : 0;
        __syncthreads();
        part[t] += v;
        __syncthreads();
    }
    int run = part[t] - s;  // exclusive prefix of this thread's chunk
    for (int i = lo; i < hi; ++i) {
        row_ptr[i] = run;
        cursor[i]  = run;
        run += cnt[i];
    }
}

__global__ __launch_bounds__(256) void fill_edges(const int* __restrict__ src,
                                                  const int* __restrict__ dst,
                                                  const int* __restrict__ et,
                                                  int* __restrict__ cursor,
                                                  int* __restrict__ epack) {
    int e = blockIdx.x * 256 + threadIdx.x;
    if (e < NE) {
        int pos = atomicAdd(&cursor[dst[e]], 1);
        epack[pos] = src[e] * 2 + et[e];  // h addr = pack*64 + lane
    }
}

// ---------------- Transform ----------------
// For each node n:
//   h[n][0][:] = act(x[n]) @ W0 ;  h[n][1][:] = act(x[n]) @ W1
//   out[n][:]  = act(x[n]) @ Ws + b   (init value for edge aggregation)
// Block = 256 threads = 4 waves; tile of 32 nodes staged in LDS; each wave
// computes 8 nodes so one W LDS read feeds 8 FMAs. Lane j owns output dim j.
// x/out may alias (in-place layer): tile rows fully read into LDS before any
// write to those rows; blocks own disjoint rows. Do NOT __restrict__ x/out.
__global__ __launch_bounds__(256) void rgcn_transform(
    const float* x, const float* __restrict__ W,
    const float* __restrict__ Ws, const float* __restrict__ bias,
    float* __restrict__ h, float* out, int relu_in)
{
    __shared__ float sW0[DIM * DIM];
    __shared__ float sW1[DIM * DIM];
    __shared__ float sWs[DIM * DIM];
    __shared__ float sX[TNODES * DIM];

    int t = threadIdx.x;
    for (int i = t; i < DIM * DIM; i += 256) {
        sW0[i] = W[i];
        sW1[i] = W[DIM * DIM + i];
        sWs[i] = Ws[i];
    }
    int lane = t & 63, wid = t >> 6;
    float bv = bias[lane];

    int n0 = blockIdx.x * TNODES;
    for (int i = t; i < TNODES * DIM; i += 256) {
        int n = n0 + (i >> 6);
        float v = (n < NN) ? x[(size_t)n * DIM + (i & 63)] : 0.f;
        if (relu_in) v = fmaxf(v, 0.f);
        sX[i] = v;
    }
    __syncthreads();

    float a0[8], a1[8], as[8];
#pragma unroll
    for (int k = 0; k < 8; ++k) { a0[k] = 0.f; a1[k] = 0.f; as[k] = bv; }

    int xbase = wid * 8 * DIM;
#pragma unroll 8
    for (int d = 0; d < DIM; ++d) {
        float w0 = sW0[d * DIM + lane];
        float w1 = sW1[d * DIM + lane];
        float ws = sWs[d * DIM + lane];
#pragma unroll
        for (int k = 0; k < 8; ++k) {
            float xv = sX[xbase + k * DIM + d];   // wave-uniform broadcast read
            a0[k] = fmaf(xv, w0, a0[k]);
            a1[k] = fmaf(xv, w1, a1[k]);
            as[k] = fmaf(xv, ws, as[k]);
        }
    }
#pragma unroll
    for (int k = 0; k < 8; ++k) {
        int n = n0 + wid * 8 + k;
        if (n < NN) {
            h[(size_t)n * (2 * DIM) + lane]       = a0[k];
            h[(size_t)n * (2 * DIM) + DIM + lane] = a1[k];
            out[(size_t)n * DIM + lane]           = as[k];
        }
    }
}

// ---------------- Gather-side aggregation (no atomics) ----------------
// One wave per node. out already holds x@Ws + b; add sum over in-edges of
// h[src][etype]. Edge list per node is contiguous (CSR); preload up to 64
// packed edges coalesced, broadcast each via __shfl.
__global__ __launch_bounds__(256) void rgcn_aggregate(
    const float* __restrict__ h, const int* __restrict__ row_ptr,
    const int* __restrict__ cnt, const int* __restrict__ epack,
    float* __restrict__ out)
{
    int t = threadIdx.x;
    int lane = t & 63, wid = t >> 6;
    int n = blockIdx.x * 4 + wid;
    if (n >= NN) return;

    int start = row_ptr[n];
    int deg   = cnt[n];
    float acc = out[(size_t)n * DIM + lane];

    for (int base = 0; base < deg; base += 64) {
        int rem = deg - base; if (rem > 64) rem = 64;
        int ev = (lane < rem) ? epack[start + base + lane] : 0;
        for (int j = 0; j < rem; ++j) {
            int p = __shfl(ev, j, 64);
            acc += h[(size_t)p * DIM + lane];  // p*64 = src*128 + et*64
        }
    }
    out[(size_t)n * DIM + lane] = acc;
}

extern "C" void kernel_launch(void* const* d_in, const int* in_sizes, int n_in,
                              void* d_out, int out_size, void* d_ws, size_t ws_size,
                              hipStream_t stream)
{
    const float* feat = (const float*)d_in[0];
    const int*   src  = (const int*)d_in[1];
    const int*   dst  = (const int*)d_in[2];
    const int*   et   = (const int*)d_in[3];
    const float* W[3]  = { (const float*)d_in[4], (const float*)d_in[7], (const float*)d_in[10] };
    const float* Ws[3] = { (const float*)d_in[5], (const float*)d_in[8], (const float*)d_in[11] };
    const float* b[3]  = { (const float*)d_in[6], (const float*)d_in[9], (const float*)d_in[12] };

    // Workspace layout (82.2 MB total):
    //   h     [NN][2][DIM] fp32   51.2 MB
    //   bufA  [NN][DIM]    fp32   25.6 MB
    //   epack [NE]         int     4.0 MB
    //   cnt / row_ptr / cursor [NN] int  3 x 0.4 MB
    float* h    = (float*)d_ws;
    float* bufA = h + (size_t)NN * 2 * DIM;
    int* epack   = (int*)(bufA + (size_t)NN * DIM);
    int* cnt     = epack + NE;
    int* row_ptr = cnt + NN;
    int* cursor  = row_ptr + NN;
    float* outF  = (float*)d_out;

    const dim3 tb(256);
    const int ngrid  = (NN + 255) / 256;       // 391
    const int egrid  = (NE + 255) / 256;       // 3907
    const int tgrid  = (NN + TNODES - 1) / TNODES;  // 3125
    const int agrid  = (NN + 3) / 4;           // 25000

    // Build CSR (same indices for all 3 layers)
    zero_counts<<<ngrid, tb, 0, stream>>>(cnt);
    count_dst<<<egrid, tb, 0, stream>>>(dst, cnt);
    scan_counts<<<1, 1024, 0, stream>>>(cnt, row_ptr, cursor);
    fill_edges<<<egrid, tb, 0, stream>>>(src, dst, et, cursor, epack);

    // Layer 0
    rgcn_transform<<<tgrid, tb, 0, stream>>>(feat, W[0], Ws[0], b[0], h, bufA, 0);
    rgcn_aggregate<<<agrid, tb, 0, stream>>>(h, row_ptr, cnt, epack, bufA);
    // Layer 1 (in-place on bufA, relu on read)
    rgcn_transform<<<tgrid, tb, 0, stream>>>(bufA, W[1], Ws[1], b[1], h, bufA, 1);
    rgcn_aggregate<<<agrid, tb, 0, stream>>>(h, row_ptr, cnt, epack, bufA);
    // Layer 2 (to d_out, relu on read, no final activation)
    rgcn_transform<<<tgrid, tb, 0, stream>>>(bufA, W[2], Ws[2], b[2], h, outF, 1);
    rgcn_aggregate<<<agrid, tb, 0, stream>>>(h, row_ptr, cnt, epack, outF);
}

// Round 3
// 630.406 us; speedup vs baseline: 1.8114x; 1.3216x over previous
//
#include <hip/hip_runtime.h>

#define NN 100000
#define NE 1000000
#define DIM 64
#define TNODES 32       // nodes per transform block tile
#define SCHUNK 1024     // elements per scan block
#define SBLOCKS ((NN + SCHUNK - 1) / SCHUNK)   // 98

// ---------------- CSR build (once per call, reused by all 3 layers) ----------
__global__ __launch_bounds__(256) void zero_counts(int* cnt) {
    int i = blockIdx.x * 256 + threadIdx.x;
    if (i < NN) cnt[i] = 0;
}

__global__ __launch_bounds__(256) void count_dst(const int* __restrict__ dst,
                                                 int* __restrict__ cnt) {
    int e = blockIdx.x * 256 + threadIdx.x;
    if (e < NE) atomicAdd(&cnt[dst[e]], 1);
}

// Scan phase 1: per-block partial sums over SCHUNK counts.
__global__ __launch_bounds__(256) void scan_partial(const int* __restrict__ cnt,
                                                    int* __restrict__ bsum) {
    int t = threadIdx.x, lane = t & 63, wid = t >> 6;
    int base = blockIdx.x * SCHUNK + t * 4;
    int s = 0;
#pragma unroll
    for (int k = 0; k < 4; ++k) {
        int i = base + k;
        if (i < NN) s += cnt[i];
    }
#pragma unroll
    for (int off = 32; off > 0; off >>= 1) s += __shfl_down(s, off, 64);
    __shared__ int wtot[4];
    if (lane == 0) wtot[wid] = s;
    __syncthreads();
    if (t == 0) bsum[blockIdx.x] = wtot[0] + wtot[1] + wtot[2] + wtot[3];
}

// Scan phase 2: one small block exclusive-scans the SBLOCKS partial sums.
__global__ __launch_bounds__(128) void scan_bsums(const int* __restrict__ bsum,
                                                  int* __restrict__ bsum_ex) {
    __shared__ int sh[128];
    int t = threadIdx.x;
    int v = (t < SBLOCKS) ? bsum[t] : 0;
    sh[t] = v;
    __syncthreads();
    for (int off = 1; off < 128; off <<= 1) {
        int u = (t >= off) ? sh[t - off] : 0;
        __syncthreads();
        sh[t] += u;
        __syncthreads();
    }
    if (t < SBLOCKS) bsum_ex[t] = sh[t] - v;   // exclusive
}

// Scan phase 3: per-block local exclusive scan + block offset -> row_ptr/cursor.
__global__ __launch_bounds__(256) void scan_final(const int* __restrict__ cnt,
                                                  const int* __restrict__ bsum_ex,
                                                  int* __restrict__ row_ptr,
                                                  int* __restrict__ cursor) {
    int t = threadIdx.x, lane = t & 63, wid = t >> 6;
    int base = blockIdx.x * SCHUNK + t * 4;
    int c[4];
#pragma unroll
    for (int k = 0; k < 4; ++k) {
        int i = base + k;
        c[k] = (i < NN) ? cnt[i] : 0;
    }
    int s = c[0] + c[1] + c[2] + c[3];
    // wave-inclusive scan of per-thread sums
    int incl = s;
#pragma unroll
    for (int off = 1; off < 64; off <<= 1) {
        int u = __shfl_up(incl, off, 64);
        if (lane >= off) incl += u;
    }
    __shared__ int wtot[4];
    if (lane == 63) wtot[wid] = incl;
    __syncthreads();
    int woff = 0;
    for (int w = 0; w < wid; ++w) woff += wtot[w];
    int run = bsum_ex[blockIdx.x] + woff + (incl - s);  // exclusive prefix for elem c[0]
#pragma unroll
    for (int k = 0; k < 4; ++k) {
        int i = base + k;
        if (i < NN) { row_ptr[i] = run; cursor[i] = run; }
        run += c[k];
    }
}

__global__ __launch_bounds__(256) void fill_edges(const int* __restrict__ src,
                                                  const int* __restrict__ dst,
                                                  const int* __restrict__ et,
                                                  int* __restrict__ cursor,
                                                  int* __restrict__ epack) {
    int e = blockIdx.x * 256 + threadIdx.x;
    if (e < NE) {
        int pos = atomicAdd(&cursor[dst[e]], 1);
        epack[pos] = src[e] * 2 + et[e];  // h addr = pack*64 + lane
    }
}

// ---------------- Transform ----------------
// For each node n:
//   h[n][0][:] = act(x[n]) @ W0 ;  h[n][1][:] = act(x[n]) @ W1
//   out[n][:]  = act(x[n]) @ Ws + b   (init value for edge aggregation)
// Block = 256 threads = 4 waves; tile of 32 nodes staged in LDS; each wave
// computes 8 nodes so one W LDS read feeds 8 FMAs. Lane j owns output dim j.
// x/out may alias (in-place layer): tile rows fully read into LDS before any
// write to those rows; blocks own disjoint rows. Do NOT __restrict__ x/out.
__global__ __launch_bounds__(256) void rgcn_transform(
    const float* x, const float* __restrict__ W,
    const float* __restrict__ Ws, const float* __restrict__ bias,
    float* __restrict__ h, float* out, int relu_in)
{
    __shared__ float sW0[DIM * DIM];
    __shared__ float sW1[DIM * DIM];
    __shared__ float sWs[DIM * DIM];
    __shared__ float sX[TNODES * DIM];

    int t = threadIdx.x;
    for (int i = t; i < DIM * DIM; i += 256) {
        sW0[i] = W[i];
        sW1[i] = W[DIM * DIM + i];
        sWs[i] = Ws[i];
    }
    int lane = t & 63, wid = t >> 6;
    float bv = bias[lane];

    int n0 = blockIdx.x * TNODES;
    for (int i = t; i < TNODES * DIM; i += 256) {
        int n = n0 + (i >> 6);
        float v = (n < NN) ? x[(size_t)n * DIM + (i & 63)] : 0.f;
        if (relu_in) v = fmaxf(v, 0.f);
        sX[i] = v;
    }
    __syncthreads();

    float a0[8], a1[8], as[8];
#pragma unroll
    for (int k = 0; k < 8; ++k) { a0[k] = 0.f; a1[k] = 0.f; as[k] = bv; }

    int xbase = wid * 8 * DIM;
#pragma unroll 8
    for (int d = 0; d < DIM; ++d) {
        float w0 = sW0[d * DIM + lane];
        float w1 = sW1[d * DIM + lane];
        float ws = sWs[d * DIM + lane];
#pragma unroll
        for (int k = 0; k < 8; ++k) {
            float xv = sX[xbase + k * DIM + d];   // wave-uniform broadcast read
            a0[k] = fmaf(xv, w0, a0[k]);
            a1[k] = fmaf(xv, w1, a1[k]);
            as[k] = fmaf(xv, ws, as[k]);
        }
    }
#pragma unroll
    for (int k = 0; k < 8; ++k) {
        int n = n0 + wid * 8 + k;
        if (n < NN) {
            h[(size_t)n * (2 * DIM) + lane]       = a0[k];
            h[(size_t)n * (2 * DIM) + DIM + lane] = a1[k];
            out[(size_t)n * DIM + lane]           = as[k];
        }
    }
}

// ---------------- Gather-side aggregation (no atomics) ----------------
// One wave per node. out already holds x@Ws + b; add sum over in-edges of
// h[src][etype]. Edge list per node is contiguous (CSR); preload up to 64
// packed edges coalesced, broadcast each via __shfl.
__global__ __launch_bounds__(256) void rgcn_aggregate(
    const float* __restrict__ h, const int* __restrict__ row_ptr,
    const int* __restrict__ cnt, const int* __restrict__ epack,
    float* __restrict__ out)
{
    int t = threadIdx.x;
    int lane = t & 63, wid = t >> 6;
    int n = blockIdx.x * 4 + wid;
    if (n >= NN) return;

    int start = row_ptr[n];
    int deg   = cnt[n];
    float acc = out[(size_t)n * DIM + lane];

    for (int base = 0; base < deg; base += 64) {
        int rem = deg - base; if (rem > 64) rem = 64;
        int ev = (lane < rem) ? epack[start + base + lane] : 0;
        for (int j = 0; j < rem; ++j) {
            int p = __shfl(ev, j, 64);
            acc += h[(size_t)p * DIM + lane];  // p*64 = src*128 + et*64
        }
    }
    out[(size_t)n * DIM + lane] = acc;
}

extern "C" void kernel_launch(void* const* d_in, const int* in_sizes, int n_in,
                              void* d_out, int out_size, void* d_ws, size_t ws_size,
                              hipStream_t stream)
{
    const float* feat = (const float*)d_in[0];
    const int*   src  = (const int*)d_in[1];
    const int*   dst  = (const int*)d_in[2];
    const int*   et   = (const int*)d_in[3];
    const float* W[3]  = { (const float*)d_in[4], (const float*)d_in[7], (const float*)d_in[10] };
    const float* Ws[3] = { (const float*)d_in[5], (const float*)d_in[8], (const float*)d_in[11] };
    const float* b[3]  = { (const float*)d_in[6], (const float*)d_in[9], (const float*)d_in[12] };

    // Workspace layout (~82.3 MB total):
    //   h     [NN][2][DIM] fp32   51.2 MB
    //   bufA  [NN][DIM]    fp32   25.6 MB
    //   epack [NE]         int     4.0 MB
    //   cnt / row_ptr / cursor [NN] int  3 x 0.4 MB
    //   bsum / bsum_ex [SBLOCKS] int
    float* h    = (float*)d_ws;
    float* bufA = h + (size_t)NN * 2 * DIM;
    int* epack   = (int*)(bufA + (size_t)NN * DIM);
    int* cnt     = epack + NE;
    int* row_ptr = cnt + NN;
    int* cursor  = row_ptr + NN;
    int* bsum    = cursor + NN;
    int* bsum_ex = bsum + SBLOCKS;
    float* outF  = (float*)d_out;

    const dim3 tb(256);
    const int ngrid  = (NN + 255) / 256;            // 391
    const int egrid  = (NE + 255) / 256;            // 3907
    const int tgrid  = (NN + TNODES - 1) / TNODES;  // 3125
    const int agrid  = (NN + 3) / 4;                // 25000

    // Build CSR (same indices for all 3 layers)
    zero_counts<<<ngrid, tb, 0, stream>>>(cnt);
    count_dst<<<egrid, tb, 0, stream>>>(dst, cnt);
    scan_partial<<<SBLOCKS, tb, 0, stream>>>(cnt, bsum);
    scan_bsums<<<1, 128, 0, stream>>>(bsum, bsum_ex);
    scan_final<<<SBLOCKS, tb, 0, stream>>>(cnt, bsum_ex, row_ptr, cursor);
    fill_edges<<<egrid, tb, 0, stream>>>(src, dst, et, cursor, epack);

    // Layer 0
    rgcn_transform<<<tgrid, tb, 0, stream>>>(feat, W[0], Ws[0], b[0], h, bufA, 0);
    rgcn_aggregate<<<agrid, tb, 0, stream>>>(h, row_ptr, cnt, epack, bufA);
    // Layer 1 (in-place on bufA, relu on read)
    rgcn_transform<<<tgrid, tb, 0, stream>>>(bufA, W[1], Ws[1], b[1], h, bufA, 1);
    rgcn_aggregate<<<agrid, tb, 0, stream>>>(h, row_ptr, cnt, epack, bufA);
    // Layer 2 (to d_out, relu on read, no final activation)
    rgcn_transform<<<tgrid, tb, 0, stream>>>(bufA, W[2], Ws[2], b[2], h, outF, 1);
    rgcn_aggregate<<<agrid, tb, 0, stream>>>(h, row_ptr, cnt, epack, outF);
}